// Round 2
// baseline (1389.384 us; speedup 1.0000x reference)
//
#include <hip/hip_runtime.h>
#include <math.h>

// Problem constants
#define Bn 32
#define Sn 2048
#define Hn 512
#define En 512
#define Mn (Bn*Sn)       // 65536 flattened [B*S] rows
#define CH 128           // s-rows per GEMM m-block == cumsum chunk size
#define NCH (Sn/CH)      // 16 chunks per batch
#define NBLK (En/128)    // 4 n-blocks
#define NG (Bn*NBLK)     // 128 chain groups (b x nblk)
#define BK 64            // GEMM K-tile
#define NT (Hn/BK)       // 8 K-steps
#define NBLOCKS (Bn*NCH*NBLK)   // 2048

using short8  = __attribute__((ext_vector_type(8))) short;   // 8 bf16 MFMA A/B frag
using floatx4 = __attribute__((ext_vector_type(4))) float;   // MFMA C/D frag

__device__ __forceinline__ unsigned short f2bf(float x) {
    unsigned u = __float_as_uint(x);
    u += 0x7FFFu + ((u >> 16) & 1u);   // RNE
    return (unsigned short)(u >> 16);
}

// pack 2 f32 -> 2 bf16 (RNE)
__device__ __forceinline__ unsigned cvt_pk_bf16(float lo, float hi) {
    unsigned r;
    asm("v_cvt_pk_bf16_f32 %0, %1, %2" : "=v"(r) : "v"(lo), "v"(hi));
    return r;
}

__device__ __forceinline__ float fast_tanh(float x) {
    x = fminf(20.f, fmaxf(-20.f, x));
    float e = __expf(2.f * x);
    return (e - 1.f) * __builtin_amdgcn_rcpf(e + 1.f);
}

// ---------------------------------------------------------------------------
// K0: fp32 -> bf16 bulk convert (Wb only). 8 elems/thread.
// ---------------------------------------------------------------------------
__global__ __launch_bounds__(256) void k_conv(const float* __restrict__ in,
                                              unsigned short* __restrict__ out, int n8) {
    int i = blockIdx.x * 256 + threadIdx.x;
    if (i >= n8) return;
    const float4 a = ((const float4*)in)[2*i];
    const float4 b = ((const float4*)in)[2*i + 1];
    short8 o;
    o[0]=f2bf(a.x); o[1]=f2bf(a.y); o[2]=f2bf(a.z); o[3]=f2bf(a.w);
    o[4]=f2bf(b.x); o[5]=f2bf(b.y); o[6]=f2bf(b.z); o[7]=f2bf(b.w);
    ((short8*)out)[i] = o;
}

// ---------------------------------------------------------------------------
// K1: w[row] = exp(dot(alpha[row,:], Wa) + ba)   one wave per row
// ---------------------------------------------------------------------------
__global__ __launch_bounds__(256) void k_w(const float* __restrict__ alpha,
                                           const float* __restrict__ Wa,
                                           const float* __restrict__ ba,
                                           float* __restrict__ wout) {
    const int lane = threadIdx.x & 63;
    const int wq   = threadIdx.x >> 6;
    const int row  = blockIdx.x * 4 + wq;
    const float* ap = alpha + (size_t)row * Hn + lane * 8;
    const float* wp = Wa + lane * 8;
    float4 a0 = *(const float4*)ap;
    float4 a1 = *(const float4*)(ap + 4);
    float4 w0 = *(const float4*)wp;
    float4 w1 = *(const float4*)(wp + 4);
    float s = a0.x*w0.x + a0.y*w0.y + a0.z*w0.z + a0.w*w0.w
            + a1.x*w1.x + a1.y*w1.y + a1.z*w1.z + a1.w*w1.w;
    #pragma unroll
    for (int off = 32; off; off >>= 1) s += __shfl_down(s, off, 64);
    if (lane == 0) wout[row] = expf(s + ba[0]);
}

// ---------------------------------------------------------------------------
// K2: cw[b,:] = inclusive cumsum_s(w[b,:]) — single-pass 256-thread block scan
//     (8 elems/thread, wave scan, cross-wave via LDS). Also zeroes the GEMM
//     chain state (status flags + ticket counter), replacing k_init.
// ---------------------------------------------------------------------------
__global__ __launch_bounds__(256) void k_scan_w(const float* __restrict__ w,
                                                float* __restrict__ cw,
                                                unsigned* __restrict__ chainst, int nst) {
    const int b   = blockIdx.x;
    const int tid = threadIdx.x;
    for (int i = b * 256 + tid; i < nst; i += Bn * 256) chainst[i] = 0u;

    const int lane = tid & 63, wq = tid >> 6;
    __shared__ float wtot[4];
    const float* wp = w + (size_t)b * Sn + tid * 8;
    float v[8];
    *(float4*)&v[0] = *(const float4*)wp;
    *(float4*)&v[4] = *(const float4*)(wp + 4);
    float s = 0.f;
    #pragma unroll
    for (int j = 0; j < 8; j++) { s += v[j]; v[j] = s; }   // in-thread inclusive
    float x = s;
    #pragma unroll
    for (int off = 1; off < 64; off <<= 1) {
        float t = __shfl_up(x, off, 64);
        if (lane >= off) x += t;
    }
    const float texcl = x - s;                             // exclusive thread prefix
    if (lane == 63) wtot[wq] = x;
    __syncthreads();
    float woff = 0.f;
    #pragma unroll
    for (int q = 0; q < 4; q++) if (q < wq) woff += wtot[q];
    float* cp = cw + (size_t)b * Sn + tid * 8;
    float4 o0, o1;
    o0.x = woff + texcl + v[0];  o0.y = woff + texcl + v[1];
    o0.z = woff + texcl + v[2];  o0.w = woff + texcl + v[3];
    o1.x = woff + texcl + v[4];  o1.y = woff + texcl + v[5];
    o1.z = woff + texcl + v[6];  o1.w = woff + texcl + v[7];
    *(float4*)cp       = o0;
    *(float4*)(cp + 4) = o1;
}

// ---------------------------------------------------------------------------
// K3 (fused): t = w*tanh(beta@Wb^T + bb)*embed, within-chunk cumsum,
// DECOUPLED-LOOKBACK cross-chunk scan, divide by cw, single write of out.
//  - A reg-staged fp32->bf16 into XOR-swizzled double-buffered LDS (32 KB)
//  - B frags read directly from L2 (Wb = 0.5 MB, fully L2-resident): no B LDS
//  - B loads issued before next-tile A loads so MFMA waits don't drain A
//  - lookback: publish chunk AGGREGATE immediately (no dependency), then sum
//    predecessor aggregates until an inclusive flag -> no retirement cascade
// ---------------------------------------------------------------------------
__global__ __launch_bounds__(256, 3) void k_gemm3(
        const float* __restrict__ Af,            // beta fp32 [Mn][Hn]
        const unsigned short* __restrict__ Bbf,  // Wb bf16 [En][Hn]
        const float* __restrict__ bbias,
        const float* __restrict__ wv,
        const float* __restrict__ cw,
        const float* __restrict__ embed,
        float* __restrict__ outp,
        float* __restrict__ aggb,                // [NG*NCH][128] chunk aggregates
        float* __restrict__ incb,                // [NG*NCH][128] inclusive prefixes
        unsigned* __restrict__ status,           // [NG*NCH] 0=none,1=agg,2=inclusive
        unsigned* __restrict__ counter)          // ticket
{
    __shared__ unsigned short lds_a[2][128 * BK];   // 2 x 16 KB A staging
    __shared__ float redbuf[256];                   // per-wave column sums
    __shared__ float offsbuf[128];                  // lookback offsets per column
    __shared__ int   sticket;

    const int tid  = threadIdx.x;
    const int lane = tid & 63, wq = tid >> 6;
    const int wave_n = wq & 1, wave_m = wq >> 1;   // 2x2 wave grid, 64x64 per wave
    const int lrow = lane & 15, quad = lane >> 4;

    if (tid == 0) sticket = (int)atomicAdd(counter, 1u);
    __syncthreads();
    const int ticket = sticket & (NBLOCKS - 1);
    const int cidx   = ticket >> 7;              // chunk-major ticket order
    const int g      = ticket & (NG - 1);
    const int bidx   = g >> 2;
    const int nblk   = g & (NBLK - 1);
    const int blockM = bidx * Sn + cidx * CH;
    const int blockN = nblk * 128;

    // A staging geometry: 8 rows x 64 cols per it; row&7 == lane>>3
    const int srow = wq * 32 + (lane >> 3);
    const int swz8 = (lane >> 3) << 3;           // row-parity XOR, element units
    const int scol = (lane & 7) * 8;
    const float* Ag = Af + (size_t)(blockM + srow) * Hn + scol;
    // per-thread B base: row = blockN + wave_n*64 + lrow (+j*16), col = quad*8
    const unsigned short* Bg = Bbf + (size_t)(blockN + wave_n*64 + lrow) * Hn + quad*8;
    const int swzr = (lrow & 7) << 3;

    floatx4 acc[4][4];
    #pragma unroll
    for (int i = 0; i < 4; i++)
        #pragma unroll
        for (int j = 0; j < 4; j++) acc[i][j] = (floatx4){0.f, 0.f, 0.f, 0.f};

    float4 areg[8];

    auto loadA = [&](int k0) {
        #pragma unroll
        for (int it = 0; it < 4; it++) {
            const float* p = Ag + (size_t)(it * 8) * Hn + k0;
            areg[2*it]     = *(const float4*)p;
            areg[2*it + 1] = *(const float4*)(p + 4);
        }
    };
    auto writeA = [&](int buf) {
        unsigned short* la = &lds_a[buf][(wq * 32) * BK + ((lane * 8) ^ swz8)];
        #pragma unroll
        for (int it = 0; it < 4; it++) {
            const float4 a = areg[2*it], b = areg[2*it + 1];
            uint4 o;
            o.x = cvt_pk_bf16(a.x, a.y);
            o.y = cvt_pk_bf16(a.z, a.w);
            o.z = cvt_pk_bf16(b.x, b.y);
            o.w = cvt_pk_bf16(b.z, b.w);
            *(uint4*)(la + it * 8 * BK) = o;
        }
    };

    // ---- pipelined main loop ----
    loadA(0);
    writeA(0);
    __syncthreads();
    #pragma unroll 2
    for (int t = 0; t < NT; ++t) {
        const int k0 = t * BK;
        // issue B frag loads (L2-resident) FIRST
        short8 bfr[8];
        #pragma unroll
        for (int kk2 = 0; kk2 < 2; kk2++)
            #pragma unroll
            for (int j = 0; j < 4; j++)
                bfr[kk2*4 + j] = *(const short8*)&Bg[(size_t)(j * 16) * Hn + k0 + kk2*32];
        // then next-tile A loads (consumed in writeA after the MFMAs)
        if (t + 1 < NT) loadA((t + 1) * BK);
        // compute current tile
        const unsigned short* la = lds_a[t & 1];
        #pragma unroll
        for (int kk2 = 0; kk2 < 2; kk2++) {
            short8 afr[4];
            #pragma unroll
            for (int i = 0; i < 4; i++)
                afr[i] = *(const short8*)&la[(wave_m*64 + i*16 + lrow)*BK
                                             + ((kk2*32 + quad*8) ^ swzr)];
            #pragma unroll
            for (int i = 0; i < 4; i++)
                #pragma unroll
                for (int j = 0; j < 4; j++)
                    acc[i][j] = __builtin_amdgcn_mfma_f32_16x16x32_bf16(
                                    afr[i], bfr[kk2*4 + j], acc[i][j], 0, 0, 0);
        }
        if (t + 1 < NT) writeA((t + 1) & 1);
        __syncthreads();
    }

    // ---- t-transform in registers: acc <- w * tanh(acc + bb) * embed ----
    const float* wvp = wv + blockM;
    const float* cwp = cw + blockM;
    float wr[4][4];
    #pragma unroll
    for (int i = 0; i < 4; i++)
        #pragma unroll
        for (int reg = 0; reg < 4; reg++)
            wr[i][reg] = wvp[wave_m*64 + i*16 + quad*4 + reg];

    #pragma unroll
    for (int j = 0; j < 4; j++) {
        const int c = blockN + wave_n*64 + j*16 + lrow;
        const float bbv = bbias[c];
        #pragma unroll
        for (int i = 0; i < 4; i++) {
            const int rl = wave_m*64 + i*16 + quad*4;
            const float* ep = embed + (size_t)(blockM + rl) * En + c;
            #pragma unroll
            for (int reg = 0; reg < 4; reg++)
                acc[i][j][reg] = wr[i][reg] * fast_tanh(acc[i][j][reg] + bbv)
                               * ep[(size_t)reg * En];
        }
    }

    // ---- per-wave column totals (64 rows each) -> redbuf ----
    float colsum[4];
    #pragma unroll
    for (int j = 0; j < 4; j++) {
        float s = 0.f;
        #pragma unroll
        for (int i = 0; i < 4; i++)
            #pragma unroll
            for (int reg = 0; reg < 4; reg++) s += acc[i][j][reg];
        s += __shfl_xor(s, 16, 64);
        s += __shfl_xor(s, 32, 64);
        colsum[j] = s;
    }
    if (lane < 16) {
        #pragma unroll
        for (int j = 0; j < 4; j++) redbuf[wq*64 + j*16 + lane] = colsum[j];
    }
    __syncthreads();

    // ---- decoupled lookback ----
    const int sidx = g * NCH + cidx;
    if (tid < 128) {
        const float agg = redbuf[tid] + redbuf[128 + tid];   // chunk column total
        if (cidx == 0) {
            offsbuf[tid] = 0.f;
            __hip_atomic_store(&incb[(size_t)sidx*128 + tid], agg,
                               __ATOMIC_RELAXED, __HIP_MEMORY_SCOPE_AGENT);
        } else {
            __hip_atomic_store(&aggb[(size_t)sidx*128 + tid], agg,
                               __ATOMIC_RELAXED, __HIP_MEMORY_SCOPE_AGENT);
        }
    }
    __threadfence();
    __syncthreads();
    if (tid == 0)
        __hip_atomic_store(&status[sidx], cidx ? 1u : 2u,
                           __ATOMIC_RELEASE, __HIP_MEMORY_SCOPE_AGENT);

    if (cidx > 0) {
        if (tid < 128) {
            float run = 0.f;
            int p = sidx - 1;
            while (true) {
                unsigned st;
                do {
                    st = __hip_atomic_load(&status[p], __ATOMIC_ACQUIRE,
                                           __HIP_MEMORY_SCOPE_AGENT);
                } while (st == 0u);
                if (st == 2u) {
                    run += __hip_atomic_load(&incb[(size_t)p*128 + tid],
                                             __ATOMIC_RELAXED, __HIP_MEMORY_SCOPE_AGENT);
                    break;
                }
                run += __hip_atomic_load(&aggb[(size_t)p*128 + tid],
                                         __ATOMIC_RELAXED, __HIP_MEMORY_SCOPE_AGENT);
                --p;       // chunk 0 is always status==2 -> terminates
            }
            offsbuf[tid] = run;
            const float agg = redbuf[tid] + redbuf[128 + tid];
            __hip_atomic_store(&incb[(size_t)sidx*128 + tid], run + agg,
                               __ATOMIC_RELAXED, __HIP_MEMORY_SCOPE_AGENT);
        }
        __threadfence();
        __syncthreads();
        if (tid == 0)
            __hip_atomic_store(&status[sidx], 2u,
                               __ATOMIC_RELEASE, __HIP_MEMORY_SCOPE_AGENT);
    }

    // ---- in-register row cumsum + divide by cw + single coherent store ----
    float drcp[4][4];
    #pragma unroll
    for (int i = 0; i < 4; i++)
        #pragma unroll
        for (int reg = 0; reg < 4; reg++)
            drcp[i][reg] = __builtin_amdgcn_rcpf(
                cwp[wave_m*64 + i*16 + quad*4 + reg] + 1e-10f);

    #pragma unroll
    for (int j = 0; j < 4; j++) {
        const int colh = wave_n*64 + j*16 + lrow;    // 0..127 within block
        const int c = blockN + colh;
        float base = offsbuf[colh];
        if (wave_m) base += redbuf[colh];            // add lower-half (rows 0-63) total
        #pragma unroll
        for (int i = 0; i < 4; i++) {
            const float p0 = acc[i][j][0];
            const float p1 = p0 + acc[i][j][1];
            const float p2 = p1 + acc[i][j][2];
            const float p3 = p2 + acc[i][j][3];
            float x = p3;
            float u = __shfl_up(x, 16, 64);
            if (quad >= 1) x += u;
            u = __shfl_up(x, 32, 64);
            if (quad >= 2) x += u;
            const float excl = x - p3;                    // exclusive-quad prefix
            const float itot = __shfl(x, 48 + lrow, 64);  // 16-row block total
            const int rl = wave_m*64 + i*16 + quad*4;
            float* op = outp + (size_t)(blockM + rl) * En + c;
            op[0]              = (base + excl + p0) * drcp[i][0];
            op[(size_t)En]     = (base + excl + p1) * drcp[i][1];
            op[(size_t)2*En]   = (base + excl + p2) * drcp[i][2];
            op[(size_t)3*En]   = (base + excl + p3) * drcp[i][3];
            base += itot;
        }
    }
}

extern "C" void kernel_launch(void* const* d_in, const int* in_sizes, int n_in,
                              void* d_out, int out_size, void* d_ws, size_t ws_size,
                              hipStream_t stream) {
    const float* alpha = (const float*)d_in[0];
    const float* beta  = (const float*)d_in[1];
    const float* embed = (const float*)d_in[2];
    const float* Wb    = (const float*)d_in[3];
    const float* bb    = (const float*)d_in[4];
    const float* Wa    = (const float*)d_in[5];
    const float* ba    = (const float*)d_in[6];
    float* out = (float*)d_out;

    // workspace layout (~3.3 MB)
    unsigned short* wb_bf = (unsigned short*)d_ws;             // En*Hn bf16 (0.5 MB)
    float* wbuf     = (float*)(wb_bf + (size_t)En * Hn);       // Mn
    float* cwbuf    = wbuf + Mn;                               // Mn
    float* aggb     = cwbuf + Mn;                              // NG*NCH*128 (1 MB)
    float* incb     = aggb + (size_t)NG * NCH * 128;           // NG*NCH*128 (1 MB)
    unsigned* status  = (unsigned*)(incb + (size_t)NG * NCH * 128); // NG*NCH
    unsigned* counter = status + NG * NCH;                     // 1 (zeroed with status)

    k_conv<<<(En * Hn / 8 + 255) / 256, 256, 0, stream>>>(Wb, wb_bf, En * Hn / 8);
    k_w<<<Mn / 4, 256, 0, stream>>>(alpha, Wa, ba, wbuf);
    k_scan_w<<<Bn, 256, 0, stream>>>(wbuf, cwbuf, status, NG * NCH + 1);
    k_gemm3<<<NBLOCKS, 256, 0, stream>>>(beta, wb_bf, bb, wbuf, cwbuf, embed,
                                         out, aggb, incb, status, counter);
}

// Round 3
// 528.650 us; speedup vs baseline: 2.6282x; 2.6282x over previous
//
#include <hip/hip_runtime.h>
#include <math.h>

// Problem constants
#define Bn 32
#define Sn 2048
#define Hn 512
#define En 512
#define Mn (Bn*Sn)       // 65536 flattened [B*S] rows
#define CH 128           // s-rows per GEMM m-block == cumsum chunk size
#define NCH (Sn/CH)      // 16 chunks per batch
#define BK 64            // GEMM K-tile
#define NT (Hn/BK)       // 8 K-steps

using short8  = __attribute__((ext_vector_type(8))) short;   // 8 bf16 MFMA A/B frag
using floatx4 = __attribute__((ext_vector_type(4))) float;   // MFMA C/D frag

__device__ __forceinline__ unsigned short f2bf(float x) {
    unsigned u = __float_as_uint(x);
    u += 0x7FFFu + ((u >> 16) & 1u);   // RNE
    return (unsigned short)(u >> 16);
}

// pack 2 f32 -> 2 bf16 (RNE)
__device__ __forceinline__ unsigned cvt_pk_bf16(float lo, float hi) {
    unsigned r;
    asm("v_cvt_pk_bf16_f32 %0, %1, %2" : "=v"(r) : "v"(lo), "v"(hi));
    return r;
}

__device__ __forceinline__ float fast_tanh(float x) {
    x = fminf(20.f, fmaxf(-20.f, x));
    float e = __expf(2.f * x);
    return (e - 1.f) * __builtin_amdgcn_rcpf(e + 1.f);
}

// ---------------------------------------------------------------------------
// K0: fp32 -> bf16 bulk convert (Wb only, 0.5 MB). 8 elems/thread.
// ---------------------------------------------------------------------------
__global__ __launch_bounds__(256) void k_conv(const float* __restrict__ in,
                                              unsigned short* __restrict__ out, int n8) {
    int i = blockIdx.x * 256 + threadIdx.x;
    if (i >= n8) return;
    const float4 a = ((const float4*)in)[2*i];
    const float4 b = ((const float4*)in)[2*i + 1];
    short8 o;
    o[0]=f2bf(a.x); o[1]=f2bf(a.y); o[2]=f2bf(a.z); o[3]=f2bf(a.w);
    o[4]=f2bf(b.x); o[5]=f2bf(b.y); o[6]=f2bf(b.z); o[7]=f2bf(b.w);
    ((short8*)out)[i] = o;
}

// ---------------------------------------------------------------------------
// K1: w[row] = exp(dot(alpha[row,:], Wa) + ba)   one wave per row
// ---------------------------------------------------------------------------
__global__ __launch_bounds__(256) void k_w(const float* __restrict__ alpha,
                                           const float* __restrict__ Wa,
                                           const float* __restrict__ ba,
                                           float* __restrict__ wout) {
    const int lane = threadIdx.x & 63;
    const int wq   = threadIdx.x >> 6;
    const int row  = blockIdx.x * 4 + wq;
    const float* ap = alpha + (size_t)row * Hn + lane * 8;
    const float* wp = Wa + lane * 8;
    float4 a0 = *(const float4*)ap;
    float4 a1 = *(const float4*)(ap + 4);
    float4 w0 = *(const float4*)wp;
    float4 w1 = *(const float4*)(wp + 4);
    float s = a0.x*w0.x + a0.y*w0.y + a0.z*w0.z + a0.w*w0.w
            + a1.x*w1.x + a1.y*w1.y + a1.z*w1.z + a1.w*w1.w;
    #pragma unroll
    for (int off = 32; off; off >>= 1) s += __shfl_down(s, off, 64);
    if (lane == 0) wout[row] = expf(s + ba[0]);
}

// ---------------------------------------------------------------------------
// K2: cw[b,:] = inclusive cumsum_s(w[b,:]) — single-pass 256-thread block scan
// ---------------------------------------------------------------------------
__global__ __launch_bounds__(256) void k_scan_w(const float* __restrict__ w,
                                                float* __restrict__ cw) {
    const int b   = blockIdx.x;
    const int tid = threadIdx.x;
    const int lane = tid & 63, wq = tid >> 6;
    __shared__ float wtot[4];
    const float* wp = w + (size_t)b * Sn + tid * 8;
    float v[8];
    *(float4*)&v[0] = *(const float4*)wp;
    *(float4*)&v[4] = *(const float4*)(wp + 4);
    float s = 0.f;
    #pragma unroll
    for (int j = 0; j < 8; j++) { s += v[j]; v[j] = s; }   // in-thread inclusive
    float x = s;
    #pragma unroll
    for (int off = 1; off < 64; off <<= 1) {
        float t = __shfl_up(x, off, 64);
        if (lane >= off) x += t;
    }
    const float texcl = x - s;                             // exclusive thread prefix
    if (lane == 63) wtot[wq] = x;
    __syncthreads();
    float woff = 0.f;
    #pragma unroll
    for (int q = 0; q < 4; q++) if (q < wq) woff += wtot[q];
    float* cp = cw + (size_t)b * Sn + tid * 8;
    float4 o0, o1;
    o0.x = woff + texcl + v[0];  o0.y = woff + texcl + v[1];
    o0.z = woff + texcl + v[2];  o0.w = woff + texcl + v[3];
    o1.x = woff + texcl + v[4];  o1.y = woff + texcl + v[5];
    o1.z = woff + texcl + v[6];  o1.w = woff + texcl + v[7];
    *(float4*)cp       = o0;
    *(float4*)(cp + 4) = o1;
}

// ---------------------------------------------------------------------------
// K3: t[r,e] = w[r]*tanh(beta[r,:]·Wb[e,:]+bb[e])*embed[r,e] -> out (as t)
//     + per-(b,chunk) column sums -> partial.  NO inter-block sync.
//  - pipelined: A(t+1) global->reg issued before compute(t); B(t) reg-loaded
//    from L2 (Wb 0.5MB resident) one step ahead; one barrier per K-step
//  - A reg-staged fp32->bf16 into XOR-swizzled double-buffered LDS (32 KB)
// ---------------------------------------------------------------------------
__global__ __launch_bounds__(256, 3) void k_gemm4(
        const float* __restrict__ Af,            // beta fp32 [Mn][Hn]
        const unsigned short* __restrict__ Bbf,  // Wb bf16 [En][Hn]
        const float* __restrict__ bbias,
        const float* __restrict__ wv,
        const float* __restrict__ embed,
        float* __restrict__ outp,                // t output [Mn][En]
        float* __restrict__ partial)             // [Bn*NCH][En] chunk column sums
{
    __shared__ unsigned short lds_a[2][128 * BK];   // 2 x 16 KB A staging
    __shared__ float redbuf[256];                   // per-wave column sums

    const int tid  = threadIdx.x;
    const int lane = tid & 63, wq = tid >> 6;
    const int wave_n = wq & 1, wave_m = wq >> 1;   // 2x2 wave grid, 64x64 per wave
    const int lrow = lane & 15, quad = lane >> 4;

    const int blockN = blockIdx.x * 128;           // 4 n-blocks (x fastest)
    const int blockM = blockIdx.y * 128;           // 512 m-blocks; never straddles b

    // A staging geometry: 8 rows x 64 cols per it; row&7 == lane>>3
    const int swz8 = (lane >> 3) << 3;             // row-parity XOR, element units
    const float* Ag = Af + (size_t)(blockM + wq * 32 + (lane >> 3)) * Hn + (lane & 7) * 8;
    // per-thread B base: row = blockN + wave_n*64 + lrow (+j*16), col = quad*8
    const unsigned short* Bg = Bbf + (size_t)(blockN + wave_n*64 + lrow) * Hn + quad*8;
    const int swzr = (lrow & 7) << 3;

    floatx4 acc[4][4];
    #pragma unroll
    for (int i = 0; i < 4; i++)
        #pragma unroll
        for (int j = 0; j < 4; j++) acc[i][j] = (floatx4){0.f, 0.f, 0.f, 0.f};

    float4 areg[8];
    short8 bfr[8];

    auto loadA = [&](int k0) {
        #pragma unroll
        for (int it = 0; it < 4; it++) {
            const float* p = Ag + (size_t)(it * 8) * Hn + k0;
            areg[2*it]     = *(const float4*)p;
            areg[2*it + 1] = *(const float4*)(p + 4);
        }
    };
    auto loadB = [&](int k0) {
        #pragma unroll
        for (int kk2 = 0; kk2 < 2; kk2++)
            #pragma unroll
            for (int j = 0; j < 4; j++)
                bfr[kk2*4 + j] = *(const short8*)&Bg[(size_t)(j * 16) * Hn + k0 + kk2*32];
    };
    auto writeA = [&](int buf) {
        unsigned short* la = &lds_a[buf][(wq * 32) * BK + ((lane * 8) ^ swz8)];
        #pragma unroll
        for (int it = 0; it < 4; it++) {
            const float4 a = areg[2*it], b = areg[2*it + 1];
            uint4 o;
            o.x = cvt_pk_bf16(a.x, a.y);
            o.y = cvt_pk_bf16(a.z, a.w);
            o.z = cvt_pk_bf16(b.x, b.y);
            o.w = cvt_pk_bf16(b.z, b.w);
            *(uint4*)(la + it * 8 * BK) = o;
        }
    };

    // ---- pipelined main loop ----
    loadA(0);
    loadB(0);
    writeA(0);        // waits A only (B issued after -> stays in flight)
    __syncthreads();
    #pragma unroll
    for (int t = 0; t < NT; ++t) {
        if (t + 1 < NT) loadA((t + 1) * BK);   // A prefetch in flight under MFMAs
        const unsigned short* la = lds_a[t & 1];
        #pragma unroll
        for (int kk2 = 0; kk2 < 2; kk2++) {
            short8 afr[4];
            #pragma unroll
            for (int i = 0; i < 4; i++)
                afr[i] = *(const short8*)&la[(wave_m*64 + i*16 + lrow)*BK
                                             + ((kk2*32 + quad*8) ^ swzr)];
            #pragma unroll
            for (int i = 0; i < 4; i++)
                #pragma unroll
                for (int j = 0; j < 4; j++)
                    acc[i][j] = __builtin_amdgcn_mfma_f32_16x16x32_bf16(
                                    afr[i], bfr[kk2*4 + j], acc[i][j], 0, 0, 0);
        }
        if (t + 1 < NT) {
            loadB((t + 1) * BK);   // after MFMAs issue: WAR-safe, full step to land
            writeA((t + 1) & 1);   // vmcnt-waits A(t+1) only; B stays in flight
            __syncthreads();
        }
    }

    // ---- t-transform in registers: acc <- w * tanh(acc + bb) * embed ----
    const float* wvp = wv + blockM;
    float wr[4][4];
    #pragma unroll
    for (int i = 0; i < 4; i++)
        #pragma unroll
        for (int reg = 0; reg < 4; reg++)
            wr[i][reg] = wvp[wave_m*64 + i*16 + quad*4 + reg];

    #pragma unroll
    for (int j = 0; j < 4; j++) {
        const int c = blockN + wave_n*64 + j*16 + lrow;
        const float bbv = bbias[c];
        #pragma unroll
        for (int i = 0; i < 4; i++) {
            const int rl = wave_m*64 + i*16 + quad*4;
            const float* ep = embed + (size_t)(blockM + rl) * En + c;
            float* op = outp + (size_t)(blockM + rl) * En + c;
            #pragma unroll
            for (int reg = 0; reg < 4; reg++) {
                const float tv = wr[i][reg] * fast_tanh(acc[i][j][reg] + bbv)
                               * ep[(size_t)reg * En];
                acc[i][j][reg] = tv;
                op[(size_t)reg * En] = tv;
            }
        }
    }

    // ---- per-wave column totals -> redbuf -> partial ----
    float colsum[4];
    #pragma unroll
    for (int j = 0; j < 4; j++) {
        float s = 0.f;
        #pragma unroll
        for (int i = 0; i < 4; i++)
            #pragma unroll
            for (int reg = 0; reg < 4; reg++) s += acc[i][j][reg];
        s += __shfl_xor(s, 16, 64);
        s += __shfl_xor(s, 32, 64);
        colsum[j] = s;
    }
    if (lane < 16) {
        #pragma unroll
        for (int j = 0; j < 4; j++) redbuf[wq*64 + j*16 + lane] = colsum[j];
    }
    __syncthreads();
    if (tid < 128) {
        const float s = redbuf[tid] + redbuf[128 + tid];   // m0 + m1 halves
        const int b     = blockM >> 11;                    // /Sn
        const int chunk = (blockM >> 7) & (NCH - 1);
        partial[((size_t)(b * NCH + chunk)) * En + blockN + tid] = s;
    }
}

// ---------------------------------------------------------------------------
// K4: per (b, chunk, 256-e-slab): offset = sum of prior chunk sums, then
//     sequential 128-step cumsum / (cw+eps), in-place in d_out. 1024 blocks.
// ---------------------------------------------------------------------------
__global__ __launch_bounds__(256) void k_cumdiv2(float* __restrict__ t,
                                                 const float* __restrict__ partial,
                                                 const float* __restrict__ cw) {
    const int eb = blockIdx.x & 1;
    const int bc = blockIdx.x >> 1;
    const int b = bc >> 4;            // /NCH
    const int chunk = bc & (NCH - 1);
    const int e = eb * 256 + threadIdx.x;
    float acc = 0.f;
    for (int c = 0; c < chunk; c++) acc += partial[((size_t)(b * NCH + c)) * En + e];
    const int s0 = chunk * CH;
    const float* cwp = cw + (size_t)b * Sn + s0;
    float* p = t + ((size_t)b * Sn + s0) * En + e;
    for (int s = 0; s < CH; s += 8) {
        float v[8], d[8];
        #pragma unroll
        for (int j = 0; j < 8; j++) v[j] = p[(size_t)(s + j) * En];
        #pragma unroll
        for (int j = 0; j < 8; j++) d[j] = cwp[s + j];
        #pragma unroll
        for (int j = 0; j < 8; j++) {
            acc += v[j];
            p[(size_t)(s + j) * En] = acc / (d[j] + 1e-10f);
        }
    }
}

extern "C" void kernel_launch(void* const* d_in, const int* in_sizes, int n_in,
                              void* d_out, int out_size, void* d_ws, size_t ws_size,
                              hipStream_t stream) {
    const float* alpha = (const float*)d_in[0];
    const float* beta  = (const float*)d_in[1];
    const float* embed = (const float*)d_in[2];
    const float* Wb    = (const float*)d_in[3];
    const float* bb    = (const float*)d_in[4];
    const float* Wa    = (const float*)d_in[5];
    const float* ba    = (const float*)d_in[6];
    float* out = (float*)d_out;

    // workspace layout (~2.1 MB)
    unsigned short* wb_bf = (unsigned short*)d_ws;             // En*Hn bf16 (0.5 MB)
    float* wbuf     = (float*)(wb_bf + (size_t)En * Hn);       // Mn
    float* cwbuf    = wbuf + Mn;                               // Mn
    float* partial  = cwbuf + Mn;                              // Bn*NCH*En (1 MB)

    k_conv<<<(En * Hn / 8 + 255) / 256, 256, 0, stream>>>(Wb, wb_bf, En * Hn / 8);
    k_w<<<Mn / 4, 256, 0, stream>>>(alpha, Wa, ba, wbuf);
    k_scan_w<<<Bn, 256, 0, stream>>>(wbuf, cwbuf);
    dim3 g3(En / 128, Mn / 128);
    k_gemm4<<<g3, 256, 0, stream>>>(beta, wb_bf, bb, wbuf, embed, out, partial);
    k_cumdiv2<<<Bn * NCH * 2, 256, 0, stream>>>(out, partial, cwbuf);
}